// Round 8
// baseline (74.118 us; speedup 1.0000x reference)
//
#include <hip/hip_runtime.h>
#include <math.h>

#define NN   8
#define INCH 32
#define INN  50000
#define OUTC 64
#define OUTN 8192
#define DD   32
#define CC   256    // NN*INCH
#define NCK  8      // j-chunks (== #XCDs)
#define CHUNK (INN / NCK)   // 6250 rows = 3.2 MB bf16 -> fits one XCD's 4MB L2

typedef unsigned short ushortT;
typedef unsigned long long ullT;

__device__ __forceinline__ unsigned f2bf_u(float f) {
  unsigned u = __float_as_uint(f);
  return (u + 0x7FFFu + ((u >> 16) & 1u)) >> 16;   // round-nearest-even
}
__device__ __forceinline__ float bf2f(ushortT b) {
  return __uint_as_float(((unsigned)b) << 16);
}

// Kernel 1: yT[j][c] bf16, NATURAL layout. Reads: 8 lanes per row -> 128B segments.
__global__ __launch_bounds__(256) void prep_kernel(
    const float* __restrict__ x, const float* __restrict__ nf, ushortT* __restrict__ yT) {
  __shared__ float tile[CC][33];   // stride 33 words: <=2-way banks all phases
  const int t = threadIdx.x;
  const int j0 = blockIdx.x * 32;
  const int jmax = min(32, INN - j0);   // 50000 = 1562*32 + 16

  const int q  = t & 7;    // j-quad within window
  const int r0 = t >> 3;   // row within 32-row group

  if (q * 4 < jmax) {
    const float4 nv = *(const float4*)(nf + (size_t)r0 * INN + j0 + 4 * q);  // loop-invariant
    #pragma unroll
    for (int p = 0; p < 8; ++p) {
      const int c = (p << 5) + r0;
      const float4 xv = *(const float4*)(x + (size_t)c * INN + j0 + 4 * q);
      float4 pr;
      pr.x = xv.x * nv.x; pr.y = xv.y * nv.y; pr.z = xv.z * nv.z; pr.w = xv.w * nv.w;
      *(float4*)&tile[c][4 * q] = pr;   // bank (r0+4q)%32 -> <=2-way
    }
  }
  __syncthreads();

  const int lane = t & 63;
  const int wave = t >> 6;
  #pragma unroll
  for (int r = 0; r < 8; ++r) {
    const int jl = wave * 8 + r;
    if (jl < jmax) {
      unsigned* dst = (unsigned*)(yT + (size_t)(j0 + jl) * CC);
      #pragma unroll
      for (int e = 0; e < 2; ++e) {
        const int c0 = 128 * e + 2 * lane;
        const unsigned lo = f2bf_u(tile[c0][jl]);      // bank (2l+jl)%32 -> 2-way (free)
        const unsigned hi = f2bf_u(tile[c0 + 1][jl]);
        dst[lane + 64 * e] = lo | (hi << 16);
      }
    }
  }
}

// Kernel S: partition each o's 32 indices by chunk -> idx16[ck][o][32] + cnts[o][ck].
// One thread per o; counts packed in a u64 (8x8-bit) to avoid runtime-indexed arrays.
__global__ __launch_bounds__(256) void sort_kernel(
    const int* __restrict__ A, ushortT* __restrict__ idx16, int* __restrict__ cnts) {
  const int o = blockIdx.x * 256 + threadIdx.x;
  ullT pack = 0;
  const int4* Ao = (const int4*)(A + (size_t)o * DD);
  #pragma unroll
  for (int qq = 0; qq < 8; ++qq) {
    const int4 v = Ao[qq];
    const int ids[4] = {v.x, v.y, v.z, v.w};
    #pragma unroll
    for (int e = 0; e < 4; ++e) {
      const int idx = ids[e];
      const int ck = idx / CHUNK;                       // magic-mul, compile-time const
      const int slot = (int)((pack >> (8 * ck)) & 0xFFULL);
      idx16[((size_t)ck * OUTN + o) * 32 + slot] = (ushortT)idx;
      pack += 1ULL << (8 * ck);
    }
  }
  #pragma unroll
  for (int ck = 0; ck < NCK; ++ck)
    cnts[(size_t)o * NCK + ck] = (int)((pack >> (8 * ck)) & 0xFFULL);
}

// Kernel 2: chunked gather, serialization-free. block b: ck=b%8 (XCD affinity),
// o-slice b/8. Wave owns an o: uniform count, uniform index loads (all lanes same
// addr), SGPR row base via readfirstlane, full-wave 512B row loads, fmax.
// Writes partial max (-inf if empty) to redp[ck][o][c] bf16, nontemporal.
__global__ __launch_bounds__(256) void gather_kernel(
    const ushortT* __restrict__ yT, const ushortT* __restrict__ idx16,
    const int* __restrict__ cnts, ushortT* __restrict__ redp) {
  const int t = threadIdx.x;
  const int lane = t & 63;
  const int wave = __builtin_amdgcn_readfirstlane(t >> 6);
  const int ck = blockIdx.x & 7;
  const int ob = blockIdx.x >> 3;

  for (int p = 0; p < 16; ++p) {
    const int o = ob * 64 + wave * 16 + p;
    const int n = __builtin_amdgcn_readfirstlane(cnts[(size_t)o * NCK + ck]);
    const ushortT* il = idx16 + ((size_t)ck * OUTN + o) * 32;

    float m0 = -INFINITY, m1 = -INFINITY, m2 = -INFINITY, m3 = -INFINITY;
    int i = 0;
    for (; i + 4 <= n; i += 4) {                 // uniform trip -> scalar branch
      const ushort4 iv = *(const ushort4*)(il + i);   // one uniform 8B load = 4 indices
      const int s0 = __builtin_amdgcn_readfirstlane((int)iv.x);
      const int s1 = __builtin_amdgcn_readfirstlane((int)iv.y);
      const int s2 = __builtin_amdgcn_readfirstlane((int)iv.z);
      const int s3 = __builtin_amdgcn_readfirstlane((int)iv.w);
      const uint2 v0 = *(const uint2*)(yT + (size_t)s0 * CC + 4 * lane);  // 512B/wave
      const uint2 v1 = *(const uint2*)(yT + (size_t)s1 * CC + 4 * lane);
      const uint2 v2 = *(const uint2*)(yT + (size_t)s2 * CC + 4 * lane);
      const uint2 v3 = *(const uint2*)(yT + (size_t)s3 * CC + 4 * lane);
      m0 = fmaxf(m0, __uint_as_float(v0.x << 16));
      m1 = fmaxf(m1, __uint_as_float(v0.x & 0xffff0000u));
      m2 = fmaxf(m2, __uint_as_float(v0.y << 16));
      m3 = fmaxf(m3, __uint_as_float(v0.y & 0xffff0000u));
      m0 = fmaxf(m0, __uint_as_float(v1.x << 16));
      m1 = fmaxf(m1, __uint_as_float(v1.x & 0xffff0000u));
      m2 = fmaxf(m2, __uint_as_float(v1.y << 16));
      m3 = fmaxf(m3, __uint_as_float(v1.y & 0xffff0000u));
      m0 = fmaxf(m0, __uint_as_float(v2.x << 16));
      m1 = fmaxf(m1, __uint_as_float(v2.x & 0xffff0000u));
      m2 = fmaxf(m2, __uint_as_float(v2.y << 16));
      m3 = fmaxf(m3, __uint_as_float(v2.y & 0xffff0000u));
      m0 = fmaxf(m0, __uint_as_float(v3.x << 16));
      m1 = fmaxf(m1, __uint_as_float(v3.x & 0xffff0000u));
      m2 = fmaxf(m2, __uint_as_float(v3.y << 16));
      m3 = fmaxf(m3, __uint_as_float(v3.y & 0xffff0000u));
    }
    for (; i < n; ++i) {
      const int s0 = __builtin_amdgcn_readfirstlane((int)il[i]);
      const uint2 v0 = *(const uint2*)(yT + (size_t)s0 * CC + 4 * lane);
      m0 = fmaxf(m0, __uint_as_float(v0.x << 16));
      m1 = fmaxf(m1, __uint_as_float(v0.x & 0xffff0000u));
      m2 = fmaxf(m2, __uint_as_float(v0.y << 16));
      m3 = fmaxf(m3, __uint_as_float(v0.y & 0xffff0000u));
    }

    // natural store c=4l..4l+3; f2bf exact (inputs already bf16; f2bf(-inf)=0xFF80)
    const ullT u =
        (ullT)(f2bf_u(m0) | (f2bf_u(m1) << 16)) |
        ((ullT)(f2bf_u(m2) | (f2bf_u(m3) << 16)) << 32);
    __builtin_nontemporal_store(
        u, (ullT*)(redp + ((size_t)ck * OUTN + o) * CC) + lane);
  }
}

// Kernel 3: merge 8 partials + out[n,k,o] = sum_i red[o][n*32+i]*ft[i][k] + bias[k][o]
__global__ __launch_bounds__(256) void out_kernel(
    const ushortT* __restrict__ redp, const float* __restrict__ ft,
    const float* __restrict__ bias, float* __restrict__ out) {
  __shared__ float rtile[64][65];   // [o_local][c_local], pad 65 -> <=2-way
  __shared__ float ftl[32][64];
  const int t = threadIdx.x;
  const int lane = t & 63;
  const int wave = t >> 6;
  const int np = blockIdx.x >> 7;   // 0..3
  const int ot = blockIdx.x & 127;  // 0..127
  const int o0 = ot * 64;
  const int c0 = np * 64;

  #pragma unroll
  for (int q = 0; q < 8; ++q) {
    const int idx = q * 256 + t;
    ftl[idx >> 6][idx & 63] = ft[idx];
  }
  // merge-load: thread covers 8 c's of a row across all 8 chunks
  #pragma unroll
  for (int i = 0; i < 2; ++i) {
    const int r = (t >> 3) + 32 * i;
    const int g = t & 7;
    float vm[8];
    #pragma unroll
    for (int u = 0; u < 8; ++u) vm[u] = -INFINITY;
    #pragma unroll
    for (int ck = 0; ck < NCK; ++ck) {
      const ushort4* src =
          (const ushort4*)(redp + ((size_t)ck * OUTN + o0 + r) * CC + c0 + g * 8);
      const ushort4 v0 = src[0];
      const ushort4 v1 = src[1];
      vm[0] = fmaxf(vm[0], bf2f(v0.x)); vm[1] = fmaxf(vm[1], bf2f(v0.y));
      vm[2] = fmaxf(vm[2], bf2f(v0.z)); vm[3] = fmaxf(vm[3], bf2f(v0.w));
      vm[4] = fmaxf(vm[4], bf2f(v1.x)); vm[5] = fmaxf(vm[5], bf2f(v1.y));
      vm[6] = fmaxf(vm[6], bf2f(v1.z)); vm[7] = fmaxf(vm[7], bf2f(v1.w));
    }
    float* dst = &rtile[r][g * 8];
    #pragma unroll
    for (int u = 0; u < 8; ++u) dst[u] = vm[u];
  }
  __syncthreads();

  const int n  = np * 2 + (wave & 1);
  const int kh = (wave >> 1) * 32;
  const int cb = (wave & 1) * 32;

  float rv[32];
  #pragma unroll
  for (int i = 0; i < 32; ++i) rv[i] = rtile[lane][cb + i];   // 2-way

  float acc[32];
  #pragma unroll
  for (int kk = 0; kk < 32; ++kk) acc[kk] = 0.f;
  #pragma unroll
  for (int i = 0; i < 32; ++i) {
    #pragma unroll
    for (int kk = 0; kk < 32; ++kk)
      acc[kk] += rv[i] * ftl[i][kh + kk];   // uniform addr -> broadcast
  }

  float* op = out + (size_t)n * OUTC * OUTN + o0 + lane;
  const float* bp = bias + o0 + lane;
  #pragma unroll
  for (int kk = 0; kk < 32; ++kk) {
    const int k = kh + kk;
    op[(size_t)k * OUTN] = acc[kk] + bp[(size_t)k * OUTN];   // 256B-contiguous stores
  }
}

extern "C" void kernel_launch(void* const* d_in, const int* in_sizes, int n_in,
                              void* d_out, int out_size, void* d_ws, size_t ws_size,
                              hipStream_t stream) {
  const float* x    = (const float*)d_in[0];
  const float* nf   = (const float*)d_in[1];
  const float* ft   = (const float*)d_in[2];
  const float* bias = (const float*)d_in[3];
  const int*   A    = (const int*)d_in[4];
  float* out = (float*)d_out;

  char* ws = (char*)d_ws;
  ushortT* yT    = (ushortT*)ws;                       // 50000*256*2  = 25.6 MB
  ws += (size_t)INN * CC * 2;
  ushortT* redp  = (ushortT*)ws;                       // 8*8192*256*2 = 33.6 MB
  ws += (size_t)NCK * OUTN * CC * 2;
  ushortT* idx16 = (ushortT*)ws;                       // 8*8192*32*2  =  4.2 MB
  ws += (size_t)NCK * OUTN * 32 * 2;
  int* cnts      = (int*)ws;                           // 8192*8*4     =  0.26 MB

  hipLaunchKernelGGL(sort_kernel,   dim3(OUTN / 256),        dim3(256), 0, stream, A, idx16, cnts);
  hipLaunchKernelGGL(prep_kernel,   dim3((INN + 31) / 32),   dim3(256), 0, stream, x, nf, yT);
  hipLaunchKernelGGL(gather_kernel, dim3((OUTN / 64) * NCK), dim3(256), 0, stream, yT, idx16, cnts, redp);
  hipLaunchKernelGGL(out_kernel,    dim3(512),               dim3(256), 0, stream, redp, ft, bias, out);
}

// Round 9
// 47.091 us; speedup vs baseline: 1.5740x; 1.5740x over previous
//
#include <hip/hip_runtime.h>
#include <math.h>

#define NN   8
#define INCH 32
#define INN  50000
#define OUTC 64
#define OUTN 8192
#define DD   32
#define CC   256            // NN*INCH
#define NPL  8              // c-planes (== #XCDs); 32 c-pairs... 16 dwords/row
#define PLDW ((size_t)INN * 16)   // dwords per plane: 50000 rows x 16 dwords(64B) = 3.2 MB

typedef unsigned short ushortT;

__device__ __forceinline__ unsigned f2bf_u(float f) {
  unsigned u = __float_as_uint(f);
  return (u + 0x7FFFu + ((u >> 16) & 1u)) >> 16;   // round-nearest-even
}

// dword convention: yTc plane p, row j, pos q (0..15) holds bf16 pair (c_lo, c_lo+128),
// c_lo = p*16 + q. So plane p serves c in {16p..16p+15} U {16p+128..16p+143}.

// Kernel 1: x*nf -> yTc (bf16 pairs). Global reads: 8 lanes/row -> 128B segments.
__global__ __launch_bounds__(256) void prep_kernel(
    const float* __restrict__ x, const float* __restrict__ nf, unsigned* __restrict__ yTc) {
  __shared__ float tile[CC][33];   // stride 33 words: <=2-way banks all phases
  const int t = threadIdx.x;
  const int j0 = blockIdx.x * 32;
  const int jmax = min(32, INN - j0);   // 50000 = 1562*32 + 16

  const int q  = t & 7;    // j-quad within window
  const int r0 = t >> 3;   // row within 32-row group

  if (q * 4 < jmax) {
    const float4 nv = *(const float4*)(nf + (size_t)r0 * INN + j0 + 4 * q);  // loop-invariant
    #pragma unroll
    for (int p = 0; p < 8; ++p) {
      const int c = (p << 5) + r0;
      const float4 xv = *(const float4*)(x + (size_t)c * INN + j0 + 4 * q);
      float4 pr;
      pr.x = xv.x * nv.x; pr.y = xv.y * nv.y; pr.z = xv.z * nv.z; pr.w = xv.w * nv.w;
      *(float4*)&tile[c][4 * q] = pr;   // bank (r0+4q)%32 -> <=2-way
    }
  }
  __syncthreads();

  const int lane = t & 63;
  const int wave = t >> 6;
  #pragma unroll
  for (int r = 0; r < 8; ++r) {
    const int jl = wave * 8 + r;
    if (jl < jmax) {
      #pragma unroll
      for (int e = 0; e < 2; ++e) {
        const int clo = lane + 64 * e;                 // 0..127
        // both reads bank (lane+jl)%32 -> 2-way (free)
        const unsigned lo = f2bf_u(tile[clo][jl]);
        const unsigned hi = f2bf_u(tile[clo + 128][jl]);
        const int pl  = clo >> 4;                      // plane 0..7
        const int pos = clo & 15;
        // per instr: 4 planes x 16 lanes x 4B = 4 aligned 64B segments
        yTc[(size_t)pl * PLDW + (size_t)(j0 + jl) * 16 + pos] = lo | (hi << 16);
      }
    }
  }
}

// Kernel 2: c-sliced gather. block b: plane ck=b%8 (XCD-pinned, 3.2MB L2-resident),
// o-group b/8 (64 o's). Lane (o_sub=l>>2, cq=l&3): max over all 32 d of its 8 c's.
// No partials -- red32 written once, final. Indices via padded-LDS broadcast.
__global__ __launch_bounds__(256) void gather_kernel(
    const unsigned* __restrict__ yTc, const int* __restrict__ A, unsigned* __restrict__ red32) {
  __shared__ int Al[64 * 33];   // A[o0..o0+63][0..31], padded: read banks conflict-free
  const int t = threadIdx.x;
  const int lane = t & 63;
  const int wave = t >> 6;
  const int ck = blockIdx.x & 7;
  const int ob = blockIdx.x >> 3;
  const int o0 = ob * 64;

  #pragma unroll
  for (int k = 0; k < 8; ++k) {
    const int f = k * 256 + t;                       // 0..2047, coalesced
    Al[(f >> 5) * 33 + (f & 31)] = A[(size_t)o0 * DD + f];
  }
  __syncthreads();

  const unsigned* plane = yTc + (size_t)ck * PLDW;
  const int osub = wave * 16 + (lane >> 2);          // 0..63
  const int cq   = lane & 3;

  float l0 = -INFINITY, l1 = -INFINITY, l2 = -INFINITY, l3 = -INFINITY;
  float h0 = -INFINITY, h1 = -INFINITY, h2 = -INFINITY, h3 = -INFINITY;

  #pragma unroll 8
  for (int d = 0; d < 32; ++d) {
    const int idx = Al[osub * 33 + d];               // bank (osub+d)%32, 4-lane broadcast
    const uint4 v = *(const uint4*)(plane + (size_t)idx * 16 + cq * 4);  // 16 x 64B segs/instr
    l0 = fmaxf(l0, __uint_as_float(v.x << 16));  h0 = fmaxf(h0, __uint_as_float(v.x & 0xffff0000u));
    l1 = fmaxf(l1, __uint_as_float(v.y << 16));  h1 = fmaxf(h1, __uint_as_float(v.y & 0xffff0000u));
    l2 = fmaxf(l2, __uint_as_float(v.z << 16));  h2 = fmaxf(h2, __uint_as_float(v.z & 0xffff0000u));
    l3 = fmaxf(l3, __uint_as_float(v.w << 16));  h3 = fmaxf(h3, __uint_as_float(v.w & 0xffff0000u));
  }

  // repack exact (values are bf16-exact): dword = lo | hi
  uint4 pk;
  pk.x = (__float_as_uint(l0) >> 16) | (__float_as_uint(h0) & 0xffff0000u);
  pk.y = (__float_as_uint(l1) >> 16) | (__float_as_uint(h1) & 0xffff0000u);
  pk.z = (__float_as_uint(l2) >> 16) | (__float_as_uint(h2) & 0xffff0000u);
  pk.w = (__float_as_uint(l3) >> 16) | (__float_as_uint(h3) & 0xffff0000u);
  // red32[o][s], s = ck*16 + cq*4 + q; per instr: 16 o's x 64B contiguous
  *(uint4*)(red32 + ((size_t)(o0 + osub) * 128) + ck * 16 + cq * 4) = pk;
}

// Kernel 3: out[n,k,o] = sum_i red[o][n*32+i]*ft[i][k] + bias[k][o]
// block: np x 64-o tile. np selects dword half: c = s (np<2, lo16) or s+128 (hi16).
__global__ __launch_bounds__(256) void out_kernel(
    const unsigned* __restrict__ red32, const float* __restrict__ ft,
    const float* __restrict__ bias, float* __restrict__ out) {
  __shared__ float rtile[64][65];   // [o_local][c_local], pad 65 -> <=2-way
  __shared__ float ftl[32][64];
  const int t = threadIdx.x;
  const int lane = t & 63;
  const int wave = t >> 6;
  const int np = blockIdx.x >> 7;   // 0..3, c0 = np*64
  const int ot = blockIdx.x & 127;  // 0..127
  const int o0 = ot * 64;
  const int hi = np >> 1;           // 0: lo16 (c<128), 1: hi16 (c>=128)
  const int sb = (np & 1) * 64;     // dword-slot base

  #pragma unroll
  for (int q = 0; q < 8; ++q) {
    const int idx = q * 256 + t;
    ftl[idx >> 6][idx & 63] = ft[idx];
  }
  // rtile fill: thread covers 8 dword-slots (32B) of a row
  #pragma unroll
  for (int i = 0; i < 2; ++i) {
    const int r = (t >> 3) + 32 * i;
    const int g = t & 7;
    const unsigned* src = red32 + (size_t)(o0 + r) * 128 + sb + g * 8;
    const uint4 v0 = *(const uint4*)(src);
    const uint4 v1 = *(const uint4*)(src + 4);
    const unsigned w[8] = {v0.x, v0.y, v0.z, v0.w, v1.x, v1.y, v1.z, v1.w};
    float* dst = &rtile[r][g * 8];   // bank (r+8g+u)%32 -> 2-way (free)
    #pragma unroll
    for (int u = 0; u < 8; ++u)
      dst[u] = __uint_as_float(hi ? (w[u] & 0xffff0000u) : (w[u] << 16));
  }
  __syncthreads();

  const int n  = np * 2 + (wave & 1);
  const int kh = (wave >> 1) * 32;
  const int cb = (wave & 1) * 32;

  float rv[32];
  #pragma unroll
  for (int i = 0; i < 32; ++i) rv[i] = rtile[lane][cb + i];   // 2-way

  float acc[32];
  #pragma unroll
  for (int kk = 0; kk < 32; ++kk) acc[kk] = 0.f;
  #pragma unroll
  for (int i = 0; i < 32; ++i) {
    #pragma unroll
    for (int kk = 0; kk < 32; ++kk)
      acc[kk] += rv[i] * ftl[i][kh + kk];   // uniform addr -> broadcast
  }

  float* op = out + (size_t)n * OUTC * OUTN + o0 + lane;
  const float* bp = bias + o0 + lane;
  #pragma unroll
  for (int kk = 0; kk < 32; ++kk) {
    const int k = kh + kk;
    op[(size_t)k * OUTN] = acc[kk] + bp[(size_t)k * OUTN];   // 256B-contiguous stores
  }
}

extern "C" void kernel_launch(void* const* d_in, const int* in_sizes, int n_in,
                              void* d_out, int out_size, void* d_ws, size_t ws_size,
                              hipStream_t stream) {
  const float* x    = (const float*)d_in[0];
  const float* nf   = (const float*)d_in[1];
  const float* ft   = (const float*)d_in[2];
  const float* bias = (const float*)d_in[3];
  const int*   A    = (const int*)d_in[4];
  float* out = (float*)d_out;

  unsigned* yTc   = (unsigned*)d_ws;                          // 8 planes x 3.2 MB = 25.6 MB
  unsigned* red32 = (unsigned*)((char*)d_ws + NPL * PLDW * 4); // 8192*128*4 = 4.2 MB

  hipLaunchKernelGGL(prep_kernel,   dim3((INN + 31) / 32),  dim3(256), 0, stream, x, nf, yTc);
  hipLaunchKernelGGL(gather_kernel, dim3((OUTN / 64) * NPL), dim3(256), 0, stream, yTc, A, red32);
  hipLaunchKernelGGL(out_kernel,    dim3(512),              dim3(256), 0, stream, red32, ft, bias, out);
}